// Round 6
// baseline (330.210 us; speedup 1.0000x reference)
//
#include <hip/hip_runtime.h>
#include <stdint.h>

typedef __attribute__((ext_vector_type(4)))  int   v4i;
typedef __attribute__((ext_vector_type(8)))  int   v8i;
typedef __attribute__((ext_vector_type(16))) float v16f;

#define BATCH 8192
#define KDIM  4096
#define NOUT  4096
#define KB    (KDIM / 2)     // bytes per packed fp4 row = 2048
#define BK_B  128            // K-tile bytes per row = 256 fp4 elems
#define NT    (KDIM / 256)   // 16 K-tiles

// pack x: fp32 -> fp4 e2m1 {x>0 -> 1.0 (0x2), else 0.0 (0x0)}, 8 elems/thread
__global__ __launch_bounds__(256) void pack_x4(const float* __restrict__ x,
                                               uint32_t* __restrict__ xb) {
    int t = blockIdx.x * 256 + threadIdx.x;
    const float4* p = (const float4*)x + (size_t)t * 2;
    float4 f0 = p[0];
    float4 f1 = p[1];
    uint32_t b = (f0.x > 0.f ? 0x2u        : 0u)
               | (f0.y > 0.f ? 0x20u       : 0u)
               | (f0.z > 0.f ? 0x200u      : 0u)
               | (f0.w > 0.f ? 0x2000u     : 0u)
               | (f1.x > 0.f ? 0x20000u    : 0u)
               | (f1.y > 0.f ? 0x200000u   : 0u)
               | (f1.z > 0.f ? 0x2000000u  : 0u)
               | (f1.w > 0.f ? 0x20000000u : 0u);
    xb[t] = b;
}

// pack W: fp32 -> fp4 e2m1 {W>0 -> +1.0 (0x2), else -1.0 (0xA)}, 8 elems/thread
__global__ __launch_bounds__(256) void pack_w4(const float* __restrict__ w,
                                               uint32_t* __restrict__ wb) {
    int t = blockIdx.x * 256 + threadIdx.x;
    const float4* p = (const float4*)w + (size_t)t * 2;
    float4 f0 = p[0];
    float4 f1 = p[1];
    uint32_t b = (f0.x > 0.f ? 0x2u        : 0xAu)
               | (f0.y > 0.f ? 0x20u       : 0xA0u)
               | (f0.z > 0.f ? 0x200u      : 0xA00u)
               | (f0.w > 0.f ? 0x2000u     : 0xA000u)
               | (f1.x > 0.f ? 0x20000u    : 0xA0000u)
               | (f1.y > 0.f ? 0x200000u   : 0xA00000u)
               | (f1.z > 0.f ? 0x2000000u  : 0xA000000u)
               | (f1.w > 0.f ? 0x20000000u : 0xA0000000u);
    wb[t] = b;
}

// C[M,N] = A[M,K] * B[N,K]^T, fp4 e2m1 (values {0,1} x {-1,+1}), f32 out —
// integer-exact via unit MX scales.
// CO-RESIDENCY structure: 4-wave (256-thr) blocks, tile 256x128, per-wave
// 128x64 (acc = 128 VGPR — same economy as R5: 24 ds_read_b128 per 32 MFMA).
// SINGLE-buffered LDS = 48 KiB/block -> 2 blocks/CU co-resident (96 KiB,
// 8 waves/CU, 2/SIMD). Per block the K-loop is serial (stage -> sync ->
// compute -> sync); overlap comes from the OTHER resident block: no barrier
// couples the two blocks, so one block's MFMA phase runs under the other's
// stage/DMA-wait (m114 mechanism). Epilogues likewise overlap.
// MFMA: 32x32x64 f8f6f4-fp4. A row = lane&31, k-chunk = lane>>5; C/D:
// col = lane&31, row = (reg&3) + 8*(reg>>2) + 4*(lane>>5)  (verified R5).
// LDS chunk XOR swizzle via pre-swizzled GLOBAL source: row r slot s holds
// global chunk s ^ (r&7); read slot for chunk c of row r is c ^ (r&7).
__global__ __launch_bounds__(256, 2) void bin_gemm4(const uint8_t* __restrict__ A,
                                                    const uint8_t* __restrict__ B,
                                                    float* __restrict__ C) {
    // A: 256 rows x 128 B = 32 KiB | B: 128 rows x 128 B = 16 KiB
    __shared__ __align__(16) uint8_t sm[49152];

    const int tid  = threadIdx.x;
    const int w    = tid >> 6;          // wave 0..3
    const int lane = tid & 63;
    const int l31  = lane & 31;         // fragment row / output col
    const int kc   = lane >> 5;         // k-chunk (16B) within 32B k-slice
    const int rsw  = lane & 7;          // (frag row) & 7, for swizzle readback

    const int Mbase = blockIdx.y * 256;
    const int Nbase = blockIdx.x * 128;
    const int wm = (w >> 1) * 128;      // wave M offset in tile
    const int wn = (w & 1) * 64;        // wave N offset in tile

    // Staging: one global_load_lds writes LDS base + lane*16 (1 KiB/wave-instr)
    // covering 8 rows x 8 chunks. Lane covers row (lane>>3), slot lane&7;
    // fetch global chunk (lane&7) ^ ((lane>>3)&7)  (group base rows %8 == 0).
    // A: wave w covers rows [w*64, w*64+64) in 8 groups; B: [w*32, w*32+32) in 4.
    const int grow = lane >> 3;
    const int swz  = ((lane & 7) ^ ((lane >> 3) & 7)) * 16;

    const uint8_t* pA = A + (size_t)(Mbase + w * 64 + grow) * KB + swz;
    const uint8_t* pB = B + (size_t)(Nbase + w * 32 + grow) * KB + swz;
    uint8_t* sA = sm;
    uint8_t* sB = sm + 32768;

    v16f acc[4][2] = {};

    for (int t = 0; t < NT; ++t) {
        const int kof = t * BK_B;

        // ---- stage tile t (single buffer): 12 loads/wave ----
        #pragma unroll
        for (int L = 0; L < 8; ++L)
            __builtin_amdgcn_global_load_lds(
                (__attribute__((address_space(1))) void*)(pA + (size_t)(L * 8) * KB + kof),
                (__attribute__((address_space(3))) void*)(sA + (w * 64 + L * 8) * 128),
                16, 0, 0);
        #pragma unroll
        for (int L = 0; L < 4; ++L)
            __builtin_amdgcn_global_load_lds(
                (__attribute__((address_space(1))) void*)(pB + (size_t)(L * 8) * KB + kof),
                (__attribute__((address_space(3))) void*)(sB + (w * 32 + L * 8) * 128),
                16, 0, 0);
        __syncthreads();    // vmcnt(0) drain + barrier: tile ready

        // ---- compute tile t: 24 ds_read_b128 + 32 MFMA (32x32x64) ----
        #pragma unroll
        for (int ks = 0; ks < 4; ++ks) {
            const int slot = ((ks * 2 + kc) ^ rsw) * 16;
            v4i bf[2];
            #pragma unroll
            for (int nb = 0; nb < 2; ++nb)
                bf[nb] = *(const v4i*)(sB + (wn + nb * 32 + l31) * 128 + slot);
            #pragma unroll
            for (int mb = 0; mb < 4; ++mb) {
                v4i af = *(const v4i*)(sA + (wm + mb * 32 + l31) * 128 + slot);
                v8i a8 = {af[0], af[1], af[2], af[3], 0, 0, 0, 0};
                #pragma unroll
                for (int nb = 0; nb < 2; ++nb) {
                    v8i b8 = {bf[nb][0], bf[nb][1], bf[nb][2], bf[nb][3], 0, 0, 0, 0};
                    acc[mb][nb] = __builtin_amdgcn_mfma_scale_f32_32x32x64_f8f6f4(
                        a8, b8, acc[mb][nb], 4, 4,
                        0, 0x7F7F7F7F, 0, 0x7F7F7F7F);
                }
            }
        }
        __syncthreads();    // all waves done reading before next overwrite
    }

    // C/D layout (shape-determined): col = lane&31,
    // row = (reg&3) + 8*(reg>>2) + 4*(lane>>5).
    float* Cp = C + (size_t)(Mbase + wm + 4 * kc) * NOUT + (Nbase + wn + l31);
    #pragma unroll
    for (int mb = 0; mb < 4; ++mb)
        #pragma unroll
        for (int nb = 0; nb < 2; ++nb)
            #pragma unroll
            for (int r = 0; r < 16; ++r)
                Cp[(size_t)(mb * 32 + (r & 3) + 8 * (r >> 2)) * NOUT + nb * 32]
                    = acc[mb][nb][r];
}

extern "C" void kernel_launch(void* const* d_in, const int* in_sizes, int n_in,
                              void* d_out, int out_size, void* d_ws, size_t ws_size,
                              hipStream_t stream) {
    const float* x = (const float*)d_in[0];   // [8192, 4096] f32
    const float* W = (const float*)d_in[1];   // [4096, 4096] f32, values +/-1
    float* out = (float*)d_out;               // [8192, 4096] f32

    uint8_t* xb = (uint8_t*)d_ws;                              // 16 MiB
    uint8_t* wb = (uint8_t*)d_ws + (size_t)BATCH * KDIM / 2;   // 8 MiB (24 MiB ws)

    pack_x4<<<(BATCH * (size_t)KDIM / 8) / 256, 256, 0, stream>>>(x, (uint32_t*)xb);
    pack_w4<<<((size_t)NOUT * KDIM / 8) / 256, 256, 0, stream>>>(W, (uint32_t*)wb);

    dim3 grid(NOUT / 128, BATCH / 256);   // (32, 32) = 1024 blocks
    bin_gemm4<<<grid, 256, 0, stream>>>(xb, wb, out);
}